// Round 14
// baseline (376.527 us; speedup 1.0000x reference)
//
#include <hip/hip_runtime.h>

namespace {
constexpr int NN = 100000;
constexpr int NE = 600000;
constexpr int H  = 128;
constexpr int SCAN_B = 256;
constexpr int NBLK_SCAN = (NN + SCAN_B - 1) / SCAN_B;  // 391
constexpr int NROWBLK192 = (NN + 191) / 192;           // 521

__global__ __launch_bounds__(256) void write_marker(float* __restrict__ out,
                                                    int n, float val) {
  int i = blockIdx.x * 256 + threadIdx.x;
  if (i < n) out[i] = val;
}

// ---------------- bottom-tier fallback (atomic path, verified) ----------------

__global__ __launch_bounds__(256) void zero_f4(float4* __restrict__ p, int n4) {
  int i = blockIdx.x * 256 + threadIdx.x;
  if (i < n4) p[i] = float4{0.f, 0.f, 0.f, 0.f};
}

__global__ __launch_bounds__(256) void scatter_l1(
    const int* __restrict__ src, const int* __restrict__ dst,
    const int* __restrict__ node_id, const float* __restrict__ embed,
    const float* __restrict__ norm, float* __restrict__ agg) {
  int idx = blockIdx.x * 256 + threadIdx.x;
  int e = idx >> 5;
  if (e >= NE) return;
  int c = (idx & 31) << 2;
  int s = src[e];
  float nrm = norm[s];
  const float4 v = *reinterpret_cast<const float4*>(embed + (size_t)node_id[s] * H + c);
  float* o = agg + (size_t)dst[e] * H + c;
  atomicAdd(o + 0, v.x * nrm);
  atomicAdd(o + 1, v.y * nrm);
  atomicAdd(o + 2, v.z * nrm);
  atomicAdd(o + 3, v.w * nrm);
}

__global__ __launch_bounds__(256) void scatter_l2(
    const int* __restrict__ src, const int* __restrict__ dst,
    const float* __restrict__ h1, const float* __restrict__ norm,
    float* __restrict__ agg) {
  int idx = blockIdx.x * 256 + threadIdx.x;
  int e = idx >> 5;
  if (e >= NE) return;
  int c = (idx & 31) << 2;
  int s = src[e];
  float nrm = norm[s];
  const float4 v = *reinterpret_cast<const float4*>(h1 + (size_t)s * H + c);
  float* o = agg + (size_t)dst[e] * H + c;
  atomicAdd(o + 0, v.x * nrm);
  atomicAdd(o + 1, v.y * nrm);
  atomicAdd(o + 2, v.z * nrm);
  atomicAdd(o + 3, v.w * nrm);
}

__global__ __launch_bounds__(128) void row_gemm_act(
    const float* __restrict__ agg, const float* __restrict__ W,
    const float* __restrict__ norm, const float* __restrict__ bias,
    float* __restrict__ out) {
  __shared__ float hs[H];
  const int row = blockIdx.x, j = threadIdx.x;
  hs[j] = agg[(size_t)row * H + j];
  __syncthreads();
  float acc = 0.f;
#pragma unroll
  for (int k = 0; k < H; ++k) acc += hs[k] * W[k * H + j];
  float v = acc * norm[row] + bias[j];
  v = v > 0.f ? v : 0.2f * v;
  out[(size_t)row * H + j] = v;
}

// ---------------- CSR build ----------------

__global__ __launch_bounds__(256) void zero_int(int* __restrict__ p, int n) {
  int i = blockIdx.x * 256 + threadIdx.x;
  if (i < n) p[i] = 0;
}

__global__ __launch_bounds__(256) void hist_dst(const int* __restrict__ dst,
                                                int* __restrict__ deg) {
  int e = blockIdx.x * 256 + threadIdx.x;
  if (e < NE) atomicAdd(&deg[dst[e]], 1);
}

__global__ __launch_bounds__(SCAN_B) void scan1(const int* __restrict__ deg,
                                                int* __restrict__ offs,
                                                int* __restrict__ bsums) {
  __shared__ int sh[SCAN_B];
  const int t = threadIdx.x;
  const int gid = blockIdx.x * SCAN_B + t;
  int v = (gid < NN) ? deg[gid] : 0;
  sh[t] = v;
  __syncthreads();
  for (int d = 1; d < SCAN_B; d <<= 1) {
    int add = (t >= d) ? sh[t - d] : 0;
    __syncthreads();
    sh[t] += add;
    __syncthreads();
  }
  if (gid < NN) offs[gid] = sh[t] - v;
  if (t == SCAN_B - 1) bsums[blockIdx.x] = sh[t];
}

// merged scan2+scan3: each block reduces bsums[0..bid) itself, adds to offs,
// seeds cnt = offs.
__global__ __launch_bounds__(256) void scan23(int* __restrict__ offs,
                                              const int* __restrict__ bsums,
                                              int* __restrict__ cnt) {
  __shared__ int sh[256];
  const int t = threadIdx.x;
  const int bid = blockIdx.x;
  int p = 0;
  if (t < bid) p += bsums[t];
  if (t + 256 < bid) p += bsums[t + 256];
  sh[t] = p;
  __syncthreads();
#pragma unroll
  for (int d = 128; d > 0; d >>= 1) {
    if (t < d) sh[t] += sh[t + d];
    __syncthreads();
  }
  const int base = sh[0];
  const int gid = bid * 256 + t;
  if (gid < NN) {
    int v = offs[gid] + base;
    offs[gid] = v;
    cnt[gid] = v;
  }
  if (gid == 0) offs[NN] = NE;
}

template <bool WITH_REC>
__global__ __launch_bounds__(256) void fill_csr(
    const int* __restrict__ src, const int* __restrict__ dst,
    const int* __restrict__ node_id, const float* __restrict__ norm,
    int* __restrict__ cnt, int* __restrict__ csr2, int2* __restrict__ rec1) {
  int e = blockIdx.x * 256 + threadIdx.x;
  if (e >= NE) return;
  int d = dst[e];
  int s = src[e];
  int pos = atomicAdd(&cnt[d], 1);
  csr2[pos] = s;
  if (WITH_REC) rec1[pos] = make_int2(node_id[s], __float_as_int(norm[s]));
}

// ---------------- gathers (no atomics; 4/2/1 ILP chains — mean deg = 6) ----------------

// L1: per-edge record {row, nrm}; 32 lanes per node, float4/lane.
__global__ __launch_bounds__(256) void gather_rec(
    const int* __restrict__ offs, const int2* __restrict__ rec,
    const float* __restrict__ h, float* __restrict__ agg) {
  const int node = blockIdx.x * 8 + (threadIdx.x >> 5);
  const int c = (threadIdx.x & 31) << 2;
  const int beg = offs[node];
  const int end = offs[node + 1];
  float4 a0{0,0,0,0}, a1{0,0,0,0}, a2{0,0,0,0}, a3{0,0,0,0};
  int i = beg;
  for (; i + 4 <= end; i += 4) {
    int2 r0 = rec[i], r1 = rec[i + 1], r2 = rec[i + 2], r3 = rec[i + 3];
    const float4 v0 = *reinterpret_cast<const float4*>(h + (size_t)r0.x * H + c);
    const float4 v1 = *reinterpret_cast<const float4*>(h + (size_t)r1.x * H + c);
    const float4 v2 = *reinterpret_cast<const float4*>(h + (size_t)r2.x * H + c);
    const float4 v3 = *reinterpret_cast<const float4*>(h + (size_t)r3.x * H + c);
    float n0 = __int_as_float(r0.y), n1 = __int_as_float(r1.y);
    float n2 = __int_as_float(r2.y), n3 = __int_as_float(r3.y);
    a0.x += v0.x * n0; a0.y += v0.y * n0; a0.z += v0.z * n0; a0.w += v0.w * n0;
    a1.x += v1.x * n1; a1.y += v1.y * n1; a1.z += v1.z * n1; a1.w += v1.w * n1;
    a2.x += v2.x * n2; a2.y += v2.y * n2; a2.z += v2.z * n2; a2.w += v2.w * n2;
    a3.x += v3.x * n3; a3.y += v3.y * n3; a3.z += v3.z * n3; a3.w += v3.w * n3;
  }
  if (i + 2 <= end) {  // 2-way middle step (deg=6 -> 4+2, no scalar tail)
    int2 r0 = rec[i], r1 = rec[i + 1];
    const float4 v0 = *reinterpret_cast<const float4*>(h + (size_t)r0.x * H + c);
    const float4 v1 = *reinterpret_cast<const float4*>(h + (size_t)r1.x * H + c);
    float n0 = __int_as_float(r0.y), n1 = __int_as_float(r1.y);
    a0.x += v0.x * n0; a0.y += v0.y * n0; a0.z += v0.z * n0; a0.w += v0.w * n0;
    a1.x += v1.x * n1; a1.y += v1.y * n1; a1.z += v1.z * n1; a1.w += v1.w * n1;
    i += 2;
  }
  if (i < end) {
    int2 r0 = rec[i];
    const float4 v0 = *reinterpret_cast<const float4*>(h + (size_t)r0.x * H + c);
    float n0 = __int_as_float(r0.y);
    a0.x += v0.x * n0; a0.y += v0.y * n0; a0.z += v0.z * n0; a0.w += v0.w * n0;
  }
  a0.x += a1.x + a2.x + a3.x;
  a0.y += a1.y + a2.y + a3.y;
  a0.z += a1.z + a2.z + a3.z;
  a0.w += a1.w + a2.w + a3.w;
  *reinterpret_cast<float4*>(agg + (size_t)node * H + c) = a0;
}

// L2: h is pre-scaled by norm (h1n), so just sum rows.
__global__ __launch_bounds__(256) void gather_idx(
    const int* __restrict__ offs, const int* __restrict__ csr,
    const float* __restrict__ h, float* __restrict__ agg) {
  const int node = blockIdx.x * 8 + (threadIdx.x >> 5);
  const int c = (threadIdx.x & 31) << 2;
  const int beg = offs[node];
  const int end = offs[node + 1];
  float4 a0{0,0,0,0}, a1{0,0,0,0}, a2{0,0,0,0}, a3{0,0,0,0};
  int i = beg;
  for (; i + 4 <= end; i += 4) {
    int s0 = csr[i], s1 = csr[i + 1], s2 = csr[i + 2], s3 = csr[i + 3];
    const float4 v0 = *reinterpret_cast<const float4*>(h + (size_t)s0 * H + c);
    const float4 v1 = *reinterpret_cast<const float4*>(h + (size_t)s1 * H + c);
    const float4 v2 = *reinterpret_cast<const float4*>(h + (size_t)s2 * H + c);
    const float4 v3 = *reinterpret_cast<const float4*>(h + (size_t)s3 * H + c);
    a0.x += v0.x; a0.y += v0.y; a0.z += v0.z; a0.w += v0.w;
    a1.x += v1.x; a1.y += v1.y; a1.z += v1.z; a1.w += v1.w;
    a2.x += v2.x; a2.y += v2.y; a2.z += v2.z; a2.w += v2.w;
    a3.x += v3.x; a3.y += v3.y; a3.z += v3.z; a3.w += v3.w;
  }
  if (i + 2 <= end) {
    int s0 = csr[i], s1 = csr[i + 1];
    const float4 v0 = *reinterpret_cast<const float4*>(h + (size_t)s0 * H + c);
    const float4 v1 = *reinterpret_cast<const float4*>(h + (size_t)s1 * H + c);
    a0.x += v0.x; a0.y += v0.y; a0.z += v0.z; a0.w += v0.w;
    a1.x += v1.x; a1.y += v1.y; a1.z += v1.z; a1.w += v1.w;
    i += 2;
  }
  if (i < end) {
    int s0 = csr[i];
    const float4 v0 = *reinterpret_cast<const float4*>(h + (size_t)s0 * H + c);
    a0.x += v0.x; a0.y += v0.y; a0.z += v0.z; a0.w += v0.w;
  }
  a0.x += a1.x + a2.x + a3.x;
  a0.y += a1.y + a2.y + a3.y;
  a0.z += a1.z + a2.z + a3.z;
  a0.w += a1.w + a2.w + a3.w;
  *reinterpret_cast<float4*>(agg + (size_t)node * H + c) = a0;
}

// mid-tier L1 gather (no records): loads node_id/norm per edge
__global__ __launch_bounds__(256) void gather_mid_l1(
    const int* __restrict__ offs, const int* __restrict__ csr,
    const int* __restrict__ node_id, const float* __restrict__ h,
    const float* __restrict__ norm, float* __restrict__ agg) {
  const int node = blockIdx.x * 8 + (threadIdx.x >> 5);
  const int c = (threadIdx.x & 31) << 2;
  const int beg = offs[node];
  const int end = offs[node + 1];
  float4 acc{0.f, 0.f, 0.f, 0.f};
  for (int i = beg; i < end; ++i) {
    int s = csr[i];
    float nrm = norm[s];
    const float4 v = *reinterpret_cast<const float4*>(h + (size_t)node_id[s] * H + c);
    acc.x += v.x * nrm; acc.y += v.y * nrm; acc.z += v.z * nrm; acc.w += v.w * nrm;
  }
  *reinterpret_cast<float4*>(agg + (size_t)node * H + c) = acc;
}

// ---------------- GEMM v9: 192 rows x 64 cols, 6 rows/thread (balanced) ----------------
// r12 model: v7's wall = LDS oversubscription. Per wave per k4: 8 ds_read_b128
// = 96 LDS-unit cyc vs 256 FMA cyc; 4 SIMDs share 1 LDS unit -> demand
// 4*96/256 = 1.5x -> VALUBusy cap 67% (meas. 49%). v9: 6 rows/thread keeps
// the SAME 8 W-reads but 384 FMA cyc -> 4*96/384 = 1.0, balanced. Extends
// v7's PROVEN named-scalar prefetch pattern (v8's a[8] array made the
// allocator drop to 72 VGPR and refetch A - r11). VGPR need ~120 < (256,3)
// cap 170 -> no forced spill (r5 lesson). Max A row touched: 520*192+191 =
// 100031 -> 51.22 MB < 53.6 MB mid-tier floor (safe overread, stores guarded).
// FMA order per output unchanged => numerics identical.

#define FMA4(ACC, S, W) \
  ACC.x += (S) * (W).x; ACC.y += (S) * (W).y; ACC.z += (S) * (W).z; ACC.w += (S) * (W).w;

#define FMAROW(ACCA, ACCB, AV)                  \
  FMA4(ACCA, AV.x, wa0) FMA4(ACCB, AV.x, wb0)   \
  FMA4(ACCA, AV.y, wa1) FMA4(ACCB, AV.y, wb1)   \
  FMA4(ACCA, AV.z, wa2) FMA4(ACCB, AV.z, wb2)   \
  FMA4(ACCA, AV.w, wa3) FMA4(ACCB, AV.w, wb3)

#define WLOADS(KB)                                                        \
  float4 wa0 = Wld[(KB) + 2 * j8],      wb0 = Wld[(KB) + 2 * j8 + 1];     \
  float4 wa1 = Wld[(KB) + 16 + 2 * j8], wb1 = Wld[(KB) + 16 + 2 * j8 + 1];\
  float4 wa2 = Wld[(KB) + 32 + 2 * j8], wb2 = Wld[(KB) + 32 + 2 * j8 + 1];\
  float4 wa3 = Wld[(KB) + 48 + 2 * j8], wb3 = Wld[(KB) + 48 + 2 * j8 + 1];

// out[row] = LReLU((agg[row] @ W) * norm[row] + b) * (SCALE_OUT ? norm[row] : 1)
template <bool SCALE_OUT>
__global__ __launch_bounds__(256, 3) void gemm_v9(
    const float* __restrict__ agg, const float* __restrict__ W,
    const float* __restrict__ norm, const float* __restrict__ bias,
    float* __restrict__ out) {
  __shared__ float4 Wld[128 * 16];  // 32 KB: [k][c], c=0..15 -> col half*64+c*4
  const int t = threadIdx.x;
  const int half = blockIdx.x & 1;           // column half (0: cols 0-63, 1: 64-127)
  const int rowBase = (blockIdx.x >> 1) * 192;

  // stage W half: 2048 float4, 8 per thread
  const float4* W4 = reinterpret_cast<const float4*>(W);
#pragma unroll
  for (int i = 0; i < 8; ++i) {
    int g = t + i * 256;            // 0..2047
    int k = g >> 4, c = g & 15;
    Wld[k * 16 + c] = W4[k * 32 + half * 16 + c];
  }
  __syncthreads();

  const int j8 = t & 7;    // col group of 8 within half
  const int r0 = t >> 3;   // 0..31; rows r0 + 32*i, i=0..5
  const float4* A4 = reinterpret_cast<const float4*>(agg) + (size_t)rowBase * 32;
  const float4* ap0 = A4 + (size_t)(r0 +   0) * 32;
  const float4* ap1 = A4 + (size_t)(r0 +  32) * 32;
  const float4* ap2 = A4 + (size_t)(r0 +  64) * 32;
  const float4* ap3 = A4 + (size_t)(r0 +  96) * 32;
  const float4* ap4 = A4 + (size_t)(r0 + 128) * 32;
  const float4* ap5 = A4 + (size_t)(r0 + 160) * 32;

  float4 accA0{0,0,0,0}, accA1{0,0,0,0}, accA2{0,0,0,0};
  float4 accA3{0,0,0,0}, accA4{0,0,0,0}, accA5{0,0,0,0};
  float4 accB0{0,0,0,0}, accB1{0,0,0,0}, accB2{0,0,0,0};
  float4 accB3{0,0,0,0}, accB4{0,0,0,0}, accB5{0,0,0,0};

  float4 c0 = ap0[0], c1 = ap1[0], c2 = ap2[0];
  float4 c3 = ap3[0], c4 = ap4[0], c5 = ap5[0];

#pragma unroll 4
  for (int k4 = 0; k4 < 31; ++k4) {
    float4 n0 = ap0[k4 + 1], n1 = ap1[k4 + 1], n2 = ap2[k4 + 1];
    float4 n3 = ap3[k4 + 1], n4 = ap4[k4 + 1], n5 = ap5[k4 + 1];
    WLOADS(k4 * 64)
    FMAROW(accA0, accB0, c0)
    FMAROW(accA1, accB1, c1)
    FMAROW(accA2, accB2, c2)
    FMAROW(accA3, accB3, c3)
    FMAROW(accA4, accB4, c4)
    FMAROW(accA5, accB5, c5)
    c0 = n0; c1 = n1; c2 = n2; c3 = n3; c4 = n4; c5 = n5;
  }
  {  // k4 = 31 (no prefetch)
    WLOADS(31 * 64)
    FMAROW(accA0, accB0, c0)
    FMAROW(accA1, accB1, c1)
    FMAROW(accA2, accB2, c2)
    FMAROW(accA3, accB3, c3)
    FMAROW(accA4, accB4, c4)
    FMAROW(accA5, accB5, c5)
  }

  const float4 bv0 = reinterpret_cast<const float4*>(bias)[half * 16 + 2 * j8];
  const float4 bv1 = reinterpret_cast<const float4*>(bias)[half * 16 + 2 * j8 + 1];

#define EMIT(I, ACCA, ACCB)                                               \
  {                                                                       \
    const int row = rowBase + r0 + 32 * (I);                              \
    if (row < NN) {                                                       \
      const float nrm = norm[row];                                        \
      float4 o0, o1;                                                      \
      o0.x = ACCA.x * nrm + bv0.x; o0.y = ACCA.y * nrm + bv0.y;           \
      o0.z = ACCA.z * nrm + bv0.z; o0.w = ACCA.w * nrm + bv0.w;           \
      o1.x = ACCB.x * nrm + bv1.x; o1.y = ACCB.y * nrm + bv1.y;           \
      o1.z = ACCB.z * nrm + bv1.z; o1.w = ACCB.w * nrm + bv1.w;           \
      o0.x = o0.x > 0.f ? o0.x : 0.2f * o0.x;                             \
      o0.y = o0.y > 0.f ? o0.y : 0.2f * o0.y;                             \
      o0.z = o0.z > 0.f ? o0.z : 0.2f * o0.z;                             \
      o0.w = o0.w > 0.f ? o0.w : 0.2f * o0.w;                             \
      o1.x = o1.x > 0.f ? o1.x : 0.2f * o1.x;                             \
      o1.y = o1.y > 0.f ? o1.y : 0.2f * o1.y;                             \
      o1.z = o1.z > 0.f ? o1.z : 0.2f * o1.z;                             \
      o1.w = o1.w > 0.f ? o1.w : 0.2f * o1.w;                             \
      if (SCALE_OUT) {                                                    \
        o0.x *= nrm; o0.y *= nrm; o0.z *= nrm; o0.w *= nrm;               \
        o1.x *= nrm; o1.y *= nrm; o1.z *= nrm; o1.w *= nrm;               \
      }                                                                   \
      float4* op =                                                        \
          reinterpret_cast<float4*>(out + (size_t)row * H + half * 64 + j8 * 8); \
      op[0] = o0;                                                         \
      op[1] = o1;                                                         \
    }                                                                     \
  }
  EMIT(0, accA0, accB0)
  EMIT(1, accA1, accB1)
  EMIT(2, accA2, accB2)
  EMIT(3, accA3, accB3)
  EMIT(4, accA4, accB4)
  EMIT(5, accA5, accB5)
#undef EMIT
}

}  // namespace

extern "C" void kernel_launch(void* const* d_in, const int* in_sizes, int n_in,
                              void* d_out, int out_size, void* d_ws, size_t ws_size,
                              hipStream_t stream) {
  float* out = (float*)d_out;                 // OUTPUT IS FP32
  const int nElem = NN * H;                   // 12.8M
  const int mkBl  = (out_size + 255) / 256;

  bool order_ok =
      (n_in == 9 && in_sizes[0] == NN && in_sizes[1] == NE && in_sizes[2] == NE &&
       in_sizes[3] == NN && in_sizes[4] == NN * H && in_sizes[5] == H * H &&
       in_sizes[6] == H && in_sizes[7] == H * H && in_sizes[8] == H);
  if (!order_ok || out_size != nElem) {
    write_marker<<<mkBl, 256, 0, stream>>>(out, out_size,
                                           (out_size != nElem) ? 300.0f : 200.0f);
    return;
  }
  if (ws_size < (size_t)nElem * 4) {
    write_marker<<<mkBl, 256, 0, stream>>>(out, out_size,
                                           2.0f + (float)(ws_size >> 20));
    return;
  }

  const int* node_id = (const int*)d_in[0];
  const int* src     = (const int*)d_in[1];
  const int* dst     = (const int*)d_in[2];
  const float* norm  = (const float*)d_in[3];
  const float* embed = (const float*)d_in[4];
  const float* W1    = (const float*)d_in[5];
  const float* b1    = (const float*)d_in[6];
  const float* W2    = (const float*)d_in[7];
  const float* b2    = (const float*)d_in[8];

  float* agg = (float*)d_ws;                             // 51.2 MB
  float* h1n = out;                                      // d_out holds h1*norm
  int2* rec1 = (int2*)((char*)d_ws + (size_t)nElem * 4); // NE x 8B (8-aligned)
  int* csr2  = (int*)(rec1 + NE);                        // NE
  int* offs  = csr2 + NE;                                // NN+1
  int* cnt   = offs + (NN + 1);                          // NN
  int* bsums = cnt + NN;                                 // 512

  const size_t need_mid =
      (size_t)nElem * 4 + ((size_t)NE + (NN + 1) + NN + 512) * 4;        // ~54.4 MB
  const size_t need_full = need_mid + (size_t)NE * 8;                    // ~59.2 MB

  const int zeroNBl = (NN + 255) / 256;
  const int edgeBl  = (NE + 255) / 256;

  if (ws_size >= need_mid) {
    const bool full = (ws_size >= need_full);
    // layout shift for mid tier: rec1 unused; csr2 right after agg
    if (!full) {
      csr2  = (int*)((char*)d_ws + (size_t)nElem * 4);
      offs  = csr2 + NE;
      cnt   = offs + (NN + 1);
      bsums = cnt + NN;
    }

    // ---- build CSR by dst (shared by both layers) ----
    zero_int<<<zeroNBl, 256, 0, stream>>>(cnt, NN);
    hist_dst<<<edgeBl, 256, 0, stream>>>(dst, cnt);
    scan1<<<NBLK_SCAN, SCAN_B, 0, stream>>>(cnt, offs, bsums);
    scan23<<<NBLK_SCAN, 256, 0, stream>>>(offs, bsums, cnt);
    if (full)
      fill_csr<true><<<edgeBl, 256, 0, stream>>>(src, dst, node_id, norm, cnt, csr2, rec1);
    else
      fill_csr<false><<<edgeBl, 256, 0, stream>>>(src, dst, node_id, norm, cnt, csr2, nullptr);

    // ---- layer 1 ----
    if (full)
      gather_rec<<<NN / 8, 256, 0, stream>>>(offs, rec1, embed, agg);
    else
      gather_mid_l1<<<NN / 8, 256, 0, stream>>>(offs, csr2, node_id, embed, norm, agg);
    gemm_v9<true><<<NROWBLK192 * 2, 256, 0, stream>>>(agg, W1, norm, b1, h1n);

    // ---- layer 2 ----
    gather_idx<<<NN / 8, 256, 0, stream>>>(offs, csr2, h1n, agg);
    gemm_v9<false><<<NROWBLK192 * 2, 256, 0, stream>>>(agg, W2, norm, b2, out);
    return;
  }

  // ---- bottom-tier fallback: atomic path ----
  const int zeroBl = (nElem / 4 + 255) / 256;
  const int scatBl = (NE * 32 + 255) / 256;

  zero_f4<<<zeroBl, 256, 0, stream>>>((float4*)agg, nElem / 4);
  scatter_l1<<<scatBl, 256, 0, stream>>>(src, dst, node_id, embed, norm, agg);
  row_gemm_act<<<NN, 128, 0, stream>>>(agg, W1, norm, b1, out);

  zero_f4<<<zeroBl, 256, 0, stream>>>((float4*)agg, nElem / 4);
  scatter_l2<<<scatBl, 256, 0, stream>>>(src, dst, out, norm, agg);
  row_gemm_act<<<NN, 128, 0, stream>>>(agg, W2, norm, b2, out);
}

// Round 15
// 365.286 us; speedup vs baseline: 1.0308x; 1.0308x over previous
//
#include <hip/hip_runtime.h>

namespace {
constexpr int NN = 100000;
constexpr int NE = 600000;
constexpr int H  = 128;
constexpr int SCAN_B = 256;
constexpr int NBLK_SCAN = (NN + SCAN_B - 1) / SCAN_B;  // 391
constexpr int NROWBLK = (NN + 127) / 128;              // 782

__global__ __launch_bounds__(256) void write_marker(float* __restrict__ out,
                                                    int n, float val) {
  int i = blockIdx.x * 256 + threadIdx.x;
  if (i < n) out[i] = val;
}

// ---------------- bottom-tier fallback (atomic path, verified) ----------------

__global__ __launch_bounds__(256) void zero_f4(float4* __restrict__ p, int n4) {
  int i = blockIdx.x * 256 + threadIdx.x;
  if (i < n4) p[i] = float4{0.f, 0.f, 0.f, 0.f};
}

__global__ __launch_bounds__(256) void scatter_l1(
    const int* __restrict__ src, const int* __restrict__ dst,
    const int* __restrict__ node_id, const float* __restrict__ embed,
    const float* __restrict__ norm, float* __restrict__ agg) {
  int idx = blockIdx.x * 256 + threadIdx.x;
  int e = idx >> 5;
  if (e >= NE) return;
  int c = (idx & 31) << 2;
  int s = src[e];
  float nrm = norm[s];
  const float4 v = *reinterpret_cast<const float4*>(embed + (size_t)node_id[s] * H + c);
  float* o = agg + (size_t)dst[e] * H + c;
  atomicAdd(o + 0, v.x * nrm);
  atomicAdd(o + 1, v.y * nrm);
  atomicAdd(o + 2, v.z * nrm);
  atomicAdd(o + 3, v.w * nrm);
}

__global__ __launch_bounds__(256) void scatter_l2(
    const int* __restrict__ src, const int* __restrict__ dst,
    const float* __restrict__ h1, const float* __restrict__ norm,
    float* __restrict__ agg) {
  int idx = blockIdx.x * 256 + threadIdx.x;
  int e = idx >> 5;
  if (e >= NE) return;
  int c = (idx & 31) << 2;
  int s = src[e];
  float nrm = norm[s];
  const float4 v = *reinterpret_cast<const float4*>(h1 + (size_t)s * H + c);
  float* o = agg + (size_t)dst[e] * H + c;
  atomicAdd(o + 0, v.x * nrm);
  atomicAdd(o + 1, v.y * nrm);
  atomicAdd(o + 2, v.z * nrm);
  atomicAdd(o + 3, v.w * nrm);
}

__global__ __launch_bounds__(128) void row_gemm_act(
    const float* __restrict__ agg, const float* __restrict__ W,
    const float* __restrict__ norm, const float* __restrict__ bias,
    float* __restrict__ out) {
  __shared__ float hs[H];
  const int row = blockIdx.x, j = threadIdx.x;
  hs[j] = agg[(size_t)row * H + j];
  __syncthreads();
  float acc = 0.f;
#pragma unroll
  for (int k = 0; k < H; ++k) acc += hs[k] * W[k * H + j];
  float v = acc * norm[row] + bias[j];
  v = v > 0.f ? v : 0.2f * v;
  out[(size_t)row * H + j] = v;
}

// ---------------- CSR build ----------------

__global__ __launch_bounds__(256) void zero_int(int* __restrict__ p, int n) {
  int i = blockIdx.x * 256 + threadIdx.x;
  if (i < n) p[i] = 0;
}

__global__ __launch_bounds__(256) void hist_dst(const int* __restrict__ dst,
                                                int* __restrict__ deg) {
  int e = blockIdx.x * 256 + threadIdx.x;
  if (e < NE) atomicAdd(&deg[dst[e]], 1);
}

__global__ __launch_bounds__(SCAN_B) void scan1(const int* __restrict__ deg,
                                                int* __restrict__ offs,
                                                int* __restrict__ bsums) {
  __shared__ int sh[SCAN_B];
  const int t = threadIdx.x;
  const int gid = blockIdx.x * SCAN_B + t;
  int v = (gid < NN) ? deg[gid] : 0;
  sh[t] = v;
  __syncthreads();
  for (int d = 1; d < SCAN_B; d <<= 1) {
    int add = (t >= d) ? sh[t - d] : 0;
    __syncthreads();
    sh[t] += add;
    __syncthreads();
  }
  if (gid < NN) offs[gid] = sh[t] - v;
  if (t == SCAN_B - 1) bsums[blockIdx.x] = sh[t];
}

// merged scan2+scan3: each block reduces bsums[0..bid) itself, adds to offs,
// seeds cnt = offs.
__global__ __launch_bounds__(256) void scan23(int* __restrict__ offs,
                                              const int* __restrict__ bsums,
                                              int* __restrict__ cnt) {
  __shared__ int sh[256];
  const int t = threadIdx.x;
  const int bid = blockIdx.x;
  int p = 0;
  if (t < bid) p += bsums[t];
  if (t + 256 < bid) p += bsums[t + 256];
  sh[t] = p;
  __syncthreads();
#pragma unroll
  for (int d = 128; d > 0; d >>= 1) {
    if (t < d) sh[t] += sh[t + d];
    __syncthreads();
  }
  const int base = sh[0];
  const int gid = bid * 256 + t;
  if (gid < NN) {
    int v = offs[gid] + base;
    offs[gid] = v;
    cnt[gid] = v;
  }
  if (gid == 0) offs[NN] = NE;
}

template <bool WITH_REC>
__global__ __launch_bounds__(256) void fill_csr(
    const int* __restrict__ src, const int* __restrict__ dst,
    const int* __restrict__ node_id, const float* __restrict__ norm,
    int* __restrict__ cnt, int* __restrict__ csr2, int2* __restrict__ rec1) {
  int e = blockIdx.x * 256 + threadIdx.x;
  if (e >= NE) return;
  int d = dst[e];
  int s = src[e];
  int pos = atomicAdd(&cnt[d], 1);
  csr2[pos] = s;
  if (WITH_REC) rec1[pos] = make_int2(node_id[s], __float_as_int(norm[s]));
}

// ---------------- gathers (no atomics; 4/2/1 ILP chains — mean deg = 6) ----------------

// L1: per-edge record {row, nrm}; 32 lanes per node, float4/lane.
__global__ __launch_bounds__(256) void gather_rec(
    const int* __restrict__ offs, const int2* __restrict__ rec,
    const float* __restrict__ h, float* __restrict__ agg) {
  const int node = blockIdx.x * 8 + (threadIdx.x >> 5);
  const int c = (threadIdx.x & 31) << 2;
  const int beg = offs[node];
  const int end = offs[node + 1];
  float4 a0{0,0,0,0}, a1{0,0,0,0}, a2{0,0,0,0}, a3{0,0,0,0};
  int i = beg;
  for (; i + 4 <= end; i += 4) {
    int2 r0 = rec[i], r1 = rec[i + 1], r2 = rec[i + 2], r3 = rec[i + 3];
    const float4 v0 = *reinterpret_cast<const float4*>(h + (size_t)r0.x * H + c);
    const float4 v1 = *reinterpret_cast<const float4*>(h + (size_t)r1.x * H + c);
    const float4 v2 = *reinterpret_cast<const float4*>(h + (size_t)r2.x * H + c);
    const float4 v3 = *reinterpret_cast<const float4*>(h + (size_t)r3.x * H + c);
    float n0 = __int_as_float(r0.y), n1 = __int_as_float(r1.y);
    float n2 = __int_as_float(r2.y), n3 = __int_as_float(r3.y);
    a0.x += v0.x * n0; a0.y += v0.y * n0; a0.z += v0.z * n0; a0.w += v0.w * n0;
    a1.x += v1.x * n1; a1.y += v1.y * n1; a1.z += v1.z * n1; a1.w += v1.w * n1;
    a2.x += v2.x * n2; a2.y += v2.y * n2; a2.z += v2.z * n2; a2.w += v2.w * n2;
    a3.x += v3.x * n3; a3.y += v3.y * n3; a3.z += v3.z * n3; a3.w += v3.w * n3;
  }
  if (i + 2 <= end) {  // 2-way middle step (deg=6 -> 4+2, no scalar tail)
    int2 r0 = rec[i], r1 = rec[i + 1];
    const float4 v0 = *reinterpret_cast<const float4*>(h + (size_t)r0.x * H + c);
    const float4 v1 = *reinterpret_cast<const float4*>(h + (size_t)r1.x * H + c);
    float n0 = __int_as_float(r0.y), n1 = __int_as_float(r1.y);
    a0.x += v0.x * n0; a0.y += v0.y * n0; a0.z += v0.z * n0; a0.w += v0.w * n0;
    a1.x += v1.x * n1; a1.y += v1.y * n1; a1.z += v1.z * n1; a1.w += v1.w * n1;
    i += 2;
  }
  if (i < end) {
    int2 r0 = rec[i];
    const float4 v0 = *reinterpret_cast<const float4*>(h + (size_t)r0.x * H + c);
    float n0 = __int_as_float(r0.y);
    a0.x += v0.x * n0; a0.y += v0.y * n0; a0.z += v0.z * n0; a0.w += v0.w * n0;
  }
  a0.x += a1.x + a2.x + a3.x;
  a0.y += a1.y + a2.y + a3.y;
  a0.z += a1.z + a2.z + a3.z;
  a0.w += a1.w + a2.w + a3.w;
  *reinterpret_cast<float4*>(agg + (size_t)node * H + c) = a0;
}

// L2: h is pre-scaled by norm (h1n), so just sum rows.
__global__ __launch_bounds__(256) void gather_idx(
    const int* __restrict__ offs, const int* __restrict__ csr,
    const float* __restrict__ h, float* __restrict__ agg) {
  const int node = blockIdx.x * 8 + (threadIdx.x >> 5);
  const int c = (threadIdx.x & 31) << 2;
  const int beg = offs[node];
  const int end = offs[node + 1];
  float4 a0{0,0,0,0}, a1{0,0,0,0}, a2{0,0,0,0}, a3{0,0,0,0};
  int i = beg;
  for (; i + 4 <= end; i += 4) {
    int s0 = csr[i], s1 = csr[i + 1], s2 = csr[i + 2], s3 = csr[i + 3];
    const float4 v0 = *reinterpret_cast<const float4*>(h + (size_t)s0 * H + c);
    const float4 v1 = *reinterpret_cast<const float4*>(h + (size_t)s1 * H + c);
    const float4 v2 = *reinterpret_cast<const float4*>(h + (size_t)s2 * H + c);
    const float4 v3 = *reinterpret_cast<const float4*>(h + (size_t)s3 * H + c);
    a0.x += v0.x; a0.y += v0.y; a0.z += v0.z; a0.w += v0.w;
    a1.x += v1.x; a1.y += v1.y; a1.z += v1.z; a1.w += v1.w;
    a2.x += v2.x; a2.y += v2.y; a2.z += v2.z; a2.w += v2.w;
    a3.x += v3.x; a3.y += v3.y; a3.z += v3.z; a3.w += v3.w;
  }
  if (i + 2 <= end) {
    int s0 = csr[i], s1 = csr[i + 1];
    const float4 v0 = *reinterpret_cast<const float4*>(h + (size_t)s0 * H + c);
    const float4 v1 = *reinterpret_cast<const float4*>(h + (size_t)s1 * H + c);
    a0.x += v0.x; a0.y += v0.y; a0.z += v0.z; a0.w += v0.w;
    a1.x += v1.x; a1.y += v1.y; a1.z += v1.z; a1.w += v1.w;
    i += 2;
  }
  if (i < end) {
    int s0 = csr[i];
    const float4 v0 = *reinterpret_cast<const float4*>(h + (size_t)s0 * H + c);
    a0.x += v0.x; a0.y += v0.y; a0.z += v0.z; a0.w += v0.w;
  }
  a0.x += a1.x + a2.x + a3.x;
  a0.y += a1.y + a2.y + a3.y;
  a0.z += a1.z + a2.z + a3.z;
  a0.w += a1.w + a2.w + a3.w;
  *reinterpret_cast<float4*>(agg + (size_t)node * H + c) = a0;
}

// mid-tier L1 gather (no records): loads node_id/norm per edge
__global__ __launch_bounds__(256) void gather_mid_l1(
    const int* __restrict__ offs, const int* __restrict__ csr,
    const int* __restrict__ node_id, const float* __restrict__ h,
    const float* __restrict__ norm, float* __restrict__ agg) {
  const int node = blockIdx.x * 8 + (threadIdx.x >> 5);
  const int c = (threadIdx.x & 31) << 2;
  const int beg = offs[node];
  const int end = offs[node + 1];
  float4 acc{0.f, 0.f, 0.f, 0.f};
  for (int i = beg; i < end; ++i) {
    int s = csr[i];
    float nrm = norm[s];
    const float4 v = *reinterpret_cast<const float4*>(h + (size_t)node_id[s] * H + c);
    acc.x += v.x * nrm; acc.y += v.y * nrm; acc.z += v.z * nrm; acc.w += v.w * nrm;
  }
  *reinterpret_cast<float4*>(agg + (size_t)node * H + c) = acc;
}

// ---------------- GEMM v7 (PROVEN 54.5 us/layer) — final configuration ----------------
// Structure history: v3 64KB-LDS 63us (occupancy-capped) / v5 no-LDS 89us (W>L1
// thrash) / v6 32KB split-N 57us / v7 +reg-prefetch 54.5us / v8 256-row 88us
// (VGPR collapse->A refetch 4x) / v9 192-row 59us (VGPR 84 < pipeline need,
// occupancy 27->19%). v7 is the measured optimum of this family; VALUBusy ~49%
// plateau resisted occupancy, prefetch, and ratio-rebalance levers.

#define FMA4(ACC, S, W) \
  ACC.x += (S) * (W).x; ACC.y += (S) * (W).y; ACC.z += (S) * (W).z; ACC.w += (S) * (W).w;

#define FMAROW(ACCA, ACCB, AV)                  \
  FMA4(ACCA, AV.x, wa0) FMA4(ACCB, AV.x, wb0)   \
  FMA4(ACCA, AV.y, wa1) FMA4(ACCB, AV.y, wb1)   \
  FMA4(ACCA, AV.z, wa2) FMA4(ACCB, AV.z, wb2)   \
  FMA4(ACCA, AV.w, wa3) FMA4(ACCB, AV.w, wb3)

#define WLOADS(KB)                                                        \
  float4 wa0 = Wld[(KB) + 2 * j8],      wb0 = Wld[(KB) + 2 * j8 + 1];     \
  float4 wa1 = Wld[(KB) + 16 + 2 * j8], wb1 = Wld[(KB) + 16 + 2 * j8 + 1];\
  float4 wa2 = Wld[(KB) + 32 + 2 * j8], wb2 = Wld[(KB) + 32 + 2 * j8 + 1];\
  float4 wa3 = Wld[(KB) + 48 + 2 * j8], wb3 = Wld[(KB) + 48 + 2 * j8 + 1];

// out[row] = LReLU((agg[row] @ W) * norm[row] + b) * (SCALE_OUT ? norm[row] : 1)
template <bool SCALE_OUT>
__global__ __launch_bounds__(256, 3) void gemm_v7(
    const float* __restrict__ agg, const float* __restrict__ W,
    const float* __restrict__ norm, const float* __restrict__ bias,
    float* __restrict__ out) {
  __shared__ float4 Wld[128 * 16];  // 32 KB: [k][c], c=0..15 -> col half*64+c*4
  const int t = threadIdx.x;
  const int half = blockIdx.x & 1;           // column half (0: cols 0-63, 1: 64-127)
  const int rowBase = (blockIdx.x >> 1) * 128;

  // stage W half: 2048 float4, 8 per thread
  const float4* W4 = reinterpret_cast<const float4*>(W);
#pragma unroll
  for (int i = 0; i < 8; ++i) {
    int g = t + i * 256;            // 0..2047
    int k = g >> 4, c = g & 15;
    Wld[k * 16 + c] = W4[k * 32 + half * 16 + c];
  }
  __syncthreads();

  const int j8 = t & 7;    // col group of 8 within half
  const int r0 = t >> 3;   // 0..31; rows r0 + 32*i, i=0..3
  const float4* A4 = reinterpret_cast<const float4*>(agg) + (size_t)rowBase * 32;
  // per-row streaming pointers (A row stride = 32 float4)
  const float4* ap0 = A4 + (size_t)(r0 +  0) * 32;
  const float4* ap1 = A4 + (size_t)(r0 + 32) * 32;
  const float4* ap2 = A4 + (size_t)(r0 + 64) * 32;
  const float4* ap3 = A4 + (size_t)(r0 + 96) * 32;

  float4 accA[4], accB[4];
#pragma unroll
  for (int i = 0; i < 4; ++i) {
    accA[i] = float4{0.f, 0.f, 0.f, 0.f};
    accB[i] = float4{0.f, 0.f, 0.f, 0.f};
  }

  // NOTE: last row-block reads A rows up to 100095 (> NN); those land inside
  // the allocated workspace (CSR arrays follow agg) so reads are safe; the
  // corresponding outputs are guarded at the store.
  float4 c0 = ap0[0], c1 = ap1[0], c2 = ap2[0], c3 = ap3[0];

#pragma unroll 4
  for (int k4 = 0; k4 < 31; ++k4) {
    // prefetch next k4 (waitcnt consumed at the swap below -> hidden by FMAs)
    float4 n0 = ap0[k4 + 1], n1 = ap1[k4 + 1], n2 = ap2[k4 + 1], n3 = ap3[k4 + 1];
    WLOADS(k4 * 64)
    FMAROW(accA[0], accB[0], c0)
    FMAROW(accA[1], accB[1], c1)
    FMAROW(accA[2], accB[2], c2)
    FMAROW(accA[3], accB[3], c3)
    c0 = n0; c1 = n1; c2 = n2; c3 = n3;
  }
  {  // k4 = 31 (no prefetch)
    WLOADS(31 * 64)
    FMAROW(accA[0], accB[0], c0)
    FMAROW(accA[1], accB[1], c1)
    FMAROW(accA[2], accB[2], c2)
    FMAROW(accA[3], accB[3], c3)
  }

  const float4 bv0 = reinterpret_cast<const float4*>(bias)[half * 16 + 2 * j8];
  const float4 bv1 = reinterpret_cast<const float4*>(bias)[half * 16 + 2 * j8 + 1];
#pragma unroll
  for (int i = 0; i < 4; ++i) {
    const int row = rowBase + r0 + 32 * i;
    if (row < NN) {
      const float nrm = norm[row];
      float4 o0, o1;
      o0.x = accA[i].x * nrm + bv0.x; o0.y = accA[i].y * nrm + bv0.y;
      o0.z = accA[i].z * nrm + bv0.z; o0.w = accA[i].w * nrm + bv0.w;
      o1.x = accB[i].x * nrm + bv1.x; o1.y = accB[i].y * nrm + bv1.y;
      o1.z = accB[i].z * nrm + bv1.z; o1.w = accB[i].w * nrm + bv1.w;
      o0.x = o0.x > 0.f ? o0.x : 0.2f * o0.x;
      o0.y = o0.y > 0.f ? o0.y : 0.2f * o0.y;
      o0.z = o0.z > 0.f ? o0.z : 0.2f * o0.z;
      o0.w = o0.w > 0.f ? o0.w : 0.2f * o0.w;
      o1.x = o1.x > 0.f ? o1.x : 0.2f * o1.x;
      o1.y = o1.y > 0.f ? o1.y : 0.2f * o1.y;
      o1.z = o1.z > 0.f ? o1.z : 0.2f * o1.z;
      o1.w = o1.w > 0.f ? o1.w : 0.2f * o1.w;
      if (SCALE_OUT) {
        o0.x *= nrm; o0.y *= nrm; o0.z *= nrm; o0.w *= nrm;
        o1.x *= nrm; o1.y *= nrm; o1.z *= nrm; o1.w *= nrm;
      }
      float4* op = reinterpret_cast<float4*>(out + (size_t)row * H + half * 64 + j8 * 8);
      op[0] = o0;
      op[1] = o1;
    }
  }
}

}  // namespace

extern "C" void kernel_launch(void* const* d_in, const int* in_sizes, int n_in,
                              void* d_out, int out_size, void* d_ws, size_t ws_size,
                              hipStream_t stream) {
  float* out = (float*)d_out;                 // OUTPUT IS FP32
  const int nElem = NN * H;                   // 12.8M
  const int mkBl  = (out_size + 255) / 256;

  bool order_ok =
      (n_in == 9 && in_sizes[0] == NN && in_sizes[1] == NE && in_sizes[2] == NE &&
       in_sizes[3] == NN && in_sizes[4] == NN * H && in_sizes[5] == H * H &&
       in_sizes[6] == H && in_sizes[7] == H * H && in_sizes[8] == H);
  if (!order_ok || out_size != nElem) {
    write_marker<<<mkBl, 256, 0, stream>>>(out, out_size,
                                           (out_size != nElem) ? 300.0f : 200.0f);
    return;
  }
  if (ws_size < (size_t)nElem * 4) {
    write_marker<<<mkBl, 256, 0, stream>>>(out, out_size,
                                           2.0f + (float)(ws_size >> 20));
    return;
  }

  const int* node_id = (const int*)d_in[0];
  const int* src     = (const int*)d_in[1];
  const int* dst     = (const int*)d_in[2];
  const float* norm  = (const float*)d_in[3];
  const float* embed = (const float*)d_in[4];
  const float* W1    = (const float*)d_in[5];
  const float* b1    = (const float*)d_in[6];
  const float* W2    = (const float*)d_in[7];
  const float* b2    = (const float*)d_in[8];

  float* agg = (float*)d_ws;                             // 51.2 MB
  float* h1n = out;                                      // d_out holds h1*norm
  int2* rec1 = (int2*)((char*)d_ws + (size_t)nElem * 4); // NE x 8B (8-aligned)
  int* csr2  = (int*)(rec1 + NE);                        // NE
  int* offs  = csr2 + NE;                                // NN+1
  int* cnt   = offs + (NN + 1);                          // NN
  int* bsums = cnt + NN;                                 // 512

  const size_t need_mid =
      (size_t)nElem * 4 + ((size_t)NE + (NN + 1) + NN + 512) * 4;        // ~54.4 MB
  const size_t need_full = need_mid + (size_t)NE * 8;                    // ~59.2 MB

  const int zeroNBl = (NN + 255) / 256;
  const int edgeBl  = (NE + 255) / 256;

  if (ws_size >= need_mid) {
    const bool full = (ws_size >= need_full);
    // layout shift for mid tier: rec1 unused; csr2 right after agg
    if (!full) {
      csr2  = (int*)((char*)d_ws + (size_t)nElem * 4);
      offs  = csr2 + NE;
      cnt   = offs + (NN + 1);
      bsums = cnt + NN;
    }

    // ---- build CSR by dst (shared by both layers) ----
    zero_int<<<zeroNBl, 256, 0, stream>>>(cnt, NN);
    hist_dst<<<edgeBl, 256, 0, stream>>>(dst, cnt);
    scan1<<<NBLK_SCAN, SCAN_B, 0, stream>>>(cnt, offs, bsums);
    scan23<<<NBLK_SCAN, 256, 0, stream>>>(offs, bsums, cnt);
    if (full)
      fill_csr<true><<<edgeBl, 256, 0, stream>>>(src, dst, node_id, norm, cnt, csr2, rec1);
    else
      fill_csr<false><<<edgeBl, 256, 0, stream>>>(src, dst, node_id, norm, cnt, csr2, nullptr);

    // ---- layer 1 ----
    if (full)
      gather_rec<<<NN / 8, 256, 0, stream>>>(offs, rec1, embed, agg);
    else
      gather_mid_l1<<<NN / 8, 256, 0, stream>>>(offs, csr2, node_id, embed, norm, agg);
    gemm_v7<true><<<NROWBLK * 2, 256, 0, stream>>>(agg, W1, norm, b1, h1n);

    // ---- layer 2 ----
    gather_idx<<<NN / 8, 256, 0, stream>>>(offs, csr2, h1n, agg);
    gemm_v7<false><<<NROWBLK * 2, 256, 0, stream>>>(agg, W2, norm, b2, out);
    return;
  }

  // ---- bottom-tier fallback: atomic path ----
  const int zeroBl = (nElem / 4 + 255) / 256;
  const int scatBl = (NE * 32 + 255) / 256;

  zero_f4<<<zeroBl, 256, 0, stream>>>((float4*)agg, nElem / 4);
  scatter_l1<<<scatBl, 256, 0, stream>>>(src, dst, node_id, embed, norm, agg);
  row_gemm_act<<<NN, 128, 0, stream>>>(agg, W1, norm, b1, out);

  zero_f4<<<zeroBl, 256, 0, stream>>>((float4*)agg, nElem / 4);
  scatter_l2<<<scatBl, 256, 0, stream>>>(src, dst, out, norm, agg);
  row_gemm_act<<<NN, 128, 0, stream>>>(agg, W2, norm, b2, out);
}